// Round 3
// baseline (5603.724 us; speedup 1.0000x reference)
//
#include <hip/hip_runtime.h>
#include <stdint.h>

// Problem dims
constexpr int NB = 64;     // batch
constexpr int NT = 32;     // time steps
constexpr int NV = 10000;  // vocab
constexpr int NE = 256;    // embed
constexpr int NH = 512;    // hidden

#define PARTITIONABLE 1

// ---------------- persistent device state (re-inited every call) -----------
// g_A[p]: concatenated activations, [k][b] layout: k<NE -> x^T, k>=NE -> h^T
__device__ float g_A[2][(NE + NH) * NB];
__device__ float g_cT[2][NH * NB];
__device__ float g_preact[4 * NH * NB];          // [gate][j][b]
__device__ unsigned int g_keys[2 * NT];          // per-step threefry keys
__device__ unsigned long long g_slots[NT * NB];  // packed argmax per (t,b)
__device__ unsigned int g_tickets[NT];           // logits last-block tickets
__device__ unsigned int g_jtick[NT * 32];        // lstm per-j-tile tickets

// ---------------- threefry2x32 (exact JAX semantics) -----------------------
__device__ __forceinline__ unsigned int rotl32(unsigned int x, int n) {
  return (x << n) | (x >> (32 - n));
}

__device__ __forceinline__ void threefry2x32(unsigned int k0, unsigned int k1,
                                             unsigned int x0, unsigned int x1,
                                             unsigned int& o0, unsigned int& o1) {
  unsigned int ks0 = k0, ks1 = k1, ks2 = k0 ^ k1 ^ 0x1BD11BDAu;
  const int R0[4] = {13, 15, 26, 6};
  const int R1[4] = {17, 29, 16, 24};
  x0 += ks0; x1 += ks1;
#pragma unroll
  for (int i = 0; i < 5; ++i) {
#pragma unroll
    for (int j = 0; j < 4; ++j) {
      const int r = ((i & 1) == 0) ? R0[j] : R1[j];
      x0 += x1; x1 = rotl32(x1, r); x1 ^= x0;
    }
    const unsigned int inj0 = (i == 0) ? ks1 : (i == 1) ? ks2 : (i == 2) ? ks0
                              : (i == 3) ? ks1 : ks2;
    const unsigned int inj1 = (i == 0) ? ks2 : (i == 1) ? ks0 : (i == 2) ? ks1
                              : (i == 3) ? ks2 : ks0;
    x0 += inj0;
    x1 += inj1 + (unsigned int)(i + 1);
  }
  o0 = x0; o1 = x1;
}

__device__ __forceinline__ float gumbel_from_bits(unsigned int bits) {
  float u = __uint_as_float((bits >> 9) | 0x3F800000u) - 1.0f;
  u = (u == 0.0f) ? 1.17549435e-38f : u;
  return -logf(-logf(u));
}

// ---------------- init: keys, state, x0, slots/tickets ---------------------
__global__ void init_kernel(const int* __restrict__ start_tok,
                            const float* __restrict__ emb) {
  const int gtid = blockIdx.x * blockDim.x + threadIdx.x;
  const int stride = gridDim.x * blockDim.x;
  if (gtid < NT) {
    unsigned int o0, o1;
#if PARTITIONABLE
    threefry2x32(0u, 42u, 0u, (unsigned int)gtid, o0, o1);
    g_keys[2 * gtid] = o0; g_keys[2 * gtid + 1] = o1;
#else
    threefry2x32(0u, 42u, (unsigned int)gtid, (unsigned int)(gtid + NT), o0, o1);
    g_keys[gtid] = o0; g_keys[gtid + NT] = o1;
#endif
  }
  for (int i = gtid; i < NT * NB; i += stride) g_slots[i] = 0ull;
  for (int i = gtid; i < NT; i += stride) g_tickets[i] = 0u;
  for (int i = gtid; i < NT * 32; i += stride) g_jtick[i] = 0u;
  for (int i = gtid; i < NE * NB; i += stride) {
    const int b = i & 63, e = i >> 6;
    const float v = emb[start_tok[b] * NE + e];
    g_A[0][i] = v; g_A[1][i] = v;
  }
  for (int i = gtid; i < NH * NB; i += stride) {
    g_A[0][NE * NB + i] = 0.0f;
    g_cT[0][i] = 0.0f;
  }
}

// ---------------- LSTM GEMM + fused gating --------------------------------
// grid (32, 4): x = 16-wide j tile, y = gate. Block covers ALL 64 batches.
// Thread: 4 j (float4 weight load) x 1 batch. K staged in 4 LDS chunks of
// 192 rows matching the old q-split boundaries; per-chunk partials summed
// left-assoc -> bit-identical preacts to rounds 1/2.
// Last gate-block per j-tile (ticket) applies sigmoid/tanh + state update.
__global__ __launch_bounds__(256) void lstm_kernel(
    int t,
    const float* __restrict__ Wi, const float* __restrict__ Ui,
    const float* __restrict__ Wf, const float* __restrict__ Uf,
    const float* __restrict__ Wog, const float* __restrict__ Uog,
    const float* __restrict__ Wc, const float* __restrict__ Uc,
    const float* __restrict__ bi, const float* __restrict__ bf,
    const float* __restrict__ bog, const float* __restrict__ bc) {
  __shared__ float as_[192 * NB];  // 48 KB chunk of A
  __shared__ int lastf;
  const int tid = threadIdx.x;
  const int jg = tid & 3;
  const int bl = tid >> 2;         // 0..63
  const int jx = blockIdx.x;
  const int g = blockIdx.y;
  const int j = jx * 16 + jg * 4;
  const float* W = (g == 0) ? Wi : (g == 1) ? Wf : (g == 2) ? Wog : Wc;
  const float* U = (g == 0) ? Ui : (g == 1) ? Uf : (g == 2) ? Uog : Uc;
  const float* A = g_A[t & 1];

  float t0 = 0.f, t1 = 0.f, t2 = 0.f, t3 = 0.f;
#pragma unroll
  for (int q = 0; q < 4; ++q) {
    __syncthreads();
    {
      const float4* src = (const float4*)(A + q * 192 * NB);
      float4* dst = (float4*)as_;
#pragma unroll
      for (int i = 0; i < 12; ++i) dst[tid + i * 256] = src[tid + i * 256];
    }
    __syncthreads();
    float a0 = 0.f, a1 = 0.f, a2 = 0.f, a3 = 0.f;
    const int r0 = q * 192, r1 = r0 + 192;
    // W rows: [r0, min(r1, NE))
    const int we = (r1 < NE) ? r1 : NE;
    for (int k = r0; k < we; k += 4) {
      float4 wv[4]; float av[4];
#pragma unroll
      for (int u = 0; u < 4; ++u) {
        wv[u] = *(const float4*)(W + (k + u) * NH + j);
        av[u] = as_[(k + u - r0) * NB + bl];
      }
#pragma unroll
      for (int u = 0; u < 4; ++u) {
        a0 = fmaf(av[u], wv[u].x, a0); a1 = fmaf(av[u], wv[u].y, a1);
        a2 = fmaf(av[u], wv[u].z, a2); a3 = fmaf(av[u], wv[u].w, a3);
      }
    }
    // U rows: [max(r0, NE), r1)
    const int us = (r0 > NE) ? r0 : NE;
    for (int k = us; k < r1; k += 4) {
      float4 wv[4]; float av[4];
#pragma unroll
      for (int u = 0; u < 4; ++u) {
        wv[u] = *(const float4*)(U + (k + u - NE) * NH + j);
        av[u] = as_[(k + u - r0) * NB + bl];
      }
#pragma unroll
      for (int u = 0; u < 4; ++u) {
        a0 = fmaf(av[u], wv[u].x, a0); a1 = fmaf(av[u], wv[u].y, a1);
        a2 = fmaf(av[u], wv[u].z, a2); a3 = fmaf(av[u], wv[u].w, a3);
      }
    }
    if (q == 0) { t0 = a0; t1 = a1; t2 = a2; t3 = a3; }
    else        { t0 += a0; t1 += a1; t2 += a2; t3 += a3; }
  }

  g_preact[(g * NH + j + 0) * NB + bl] = t0;
  g_preact[(g * NH + j + 1) * NB + bl] = t1;
  g_preact[(g * NH + j + 2) * NB + bl] = t2;
  g_preact[(g * NH + j + 3) * NB + bl] = t3;

  __syncthreads();
  __threadfence();
  if (tid == 0) {
    lastf = (atomicAdd(&g_jtick[t * 32 + jx], 1u) == 3u) ? 1 : 0;
  }
  __syncthreads();
  if (lastf) {
    __threadfence();  // acquire other gate-blocks' preact writes
    const int b = tid & 63;
    const int cb = jx * 16 + (tid >> 6) * 4;
#pragma unroll
    for (int jj = 0; jj < 4; ++jj) {
      const int col = cb + jj;
      const int idx = col * NB + b;
      const float zi = g_preact[0 * NH * NB + idx] + bi[col];
      const float zf = g_preact[1 * NH * NB + idx] + bf[col];
      const float zo = g_preact[2 * NH * NB + idx] + bog[col];
      const float zc = g_preact[3 * NH * NB + idx] + bc[col];
      const float iv = 1.0f / (1.0f + expf(-zi));
      const float fv = 1.0f / (1.0f + expf(-zf));
      const float ov = 1.0f / (1.0f + expf(-zo));
      const float cc = tanhf(zc);
      const float cold = g_cT[t & 1][idx];
      const float cn = fv * cold + iv * cc;
      g_cT[(t & 1) ^ 1][idx] = cn;
      g_A[(t & 1) ^ 1][NE * NB + idx] = ov * tanhf(cn);
    }
  }
}

// ---------------- logits + gumbel + argmax + finalize ----------------------
// grid (313): 32-wide vocab tile; block covers ALL 64 batches.
// Thread: 4 vocab (float4 Wo) x 2 batch (float2 LDS h). h staged in 4 chunks
// of 128 rows (32 KB LDS). Per-output k-chain strictly sequential 0..511 ->
// bit-identical logits to rounds 1/2. Wo read exactly once per step.
__global__ __launch_bounds__(256) void logits_kernel(
    int t, const int* __restrict__ input_x, const int* __restrict__ given_p,
    const float* __restrict__ emb, const float* __restrict__ Wo,
    const float* __restrict__ bo, int* __restrict__ out) {
  __shared__ float hs[128 * NB];  // 32 KB chunk of h
  __shared__ unsigned long long best[NB];
  __shared__ int toksh[NB];
  __shared__ int flag;
  const int tid = threadIdx.x;
  const int given = *given_p;

  if (t >= given) {
    const float* hT = g_A[(t & 1) ^ 1] + NE * NB;
    const int vg = tid & 7;
    const int bl0 = (tid >> 3) * 2;
    const int n = blockIdx.x * 32 + vg * 4;
    const bool nv = (n < NV);
    const int nl = nv ? n : 0;
    const float* wp = Wo + nl;

    if (tid < NB) best[tid] = 0ull;

    float a00 = 0.f, a01 = 0.f, a02 = 0.f, a03 = 0.f;
    float a10 = 0.f, a11 = 0.f, a12 = 0.f, a13 = 0.f;
#pragma unroll
    for (int kc = 0; kc < 4; ++kc) {
      __syncthreads();
      {
        const float4* src = (const float4*)(hT + kc * 128 * NB);
        float4* dst = (float4*)hs;
#pragma unroll
        for (int i = 0; i < 8; ++i) dst[tid + i * 256] = src[tid + i * 256];
      }
      __syncthreads();
      const float* wpc = wp + (size_t)kc * 128 * NV;
      for (int kk = 0; kk < 128; kk += 8) {
        float4 wv[8]; float2 hv[8];
#pragma unroll
        for (int u = 0; u < 8; ++u) {
          wv[u] = *(const float4*)(wpc + (size_t)(kk + u) * NV);
          hv[u] = *(const float2*)(hs + (kk + u) * NB + bl0);
        }
#pragma unroll
        for (int u = 0; u < 8; ++u) {
          a00 = fmaf(hv[u].x, wv[u].x, a00); a01 = fmaf(hv[u].x, wv[u].y, a01);
          a02 = fmaf(hv[u].x, wv[u].z, a02); a03 = fmaf(hv[u].x, wv[u].w, a03);
          a10 = fmaf(hv[u].y, wv[u].x, a10); a11 = fmaf(hv[u].y, wv[u].y, a11);
          a12 = fmaf(hv[u].y, wv[u].z, a12); a13 = fmaf(hv[u].y, wv[u].w, a13);
        }
      }
    }

    if (nv) {
      const unsigned int key0 = g_keys[2 * t], key1 = g_keys[2 * t + 1];
      const float4 bo4 = *(const float4*)(bo + nl);
      const float accs[2][4] = {{a00 + bo4.x, a01 + bo4.y, a02 + bo4.z, a03 + bo4.w},
                                {a10 + bo4.x, a11 + bo4.y, a12 + bo4.z, a13 + bo4.w}};
#pragma unroll
      for (int s = 0; s < 2; ++s) {
        const int bg = bl0 + s;
        unsigned long long bp = 0ull;
#pragma unroll
        for (int jj = 0; jj < 4; ++jj) {
          const int v = n + jj;
          unsigned int u0, u1, bits;
#if PARTITIONABLE
          threefry2x32(key0, key1, 0u, (unsigned int)(bg * NV + v), u0, u1);
          bits = u0 ^ u1;
#else
          const int p = bg * NV + v;
          const unsigned int c = (unsigned int)(p >= (NB / 2) * NV ? p - (NB / 2) * NV : p);
          threefry2x32(key0, key1, c, c + (unsigned int)((NB / 2) * NV), u0, u1);
          bits = (p >= (NB / 2) * NV) ? u1 : u0;
#endif
          const float val = gumbel_from_bits(bits) + accs[s][jj];
          const unsigned int fb = __float_as_uint(val);
          const unsigned int ord = (fb & 0x80000000u) ? ~fb : (fb | 0x80000000u);
          const unsigned long long pk =
              ((unsigned long long)ord << 32) | (unsigned int)(~v);
          bp = (pk > bp) ? pk : bp;
        }
        atomicMax(&best[bg], bp);
      }
    }
    __syncthreads();
    if (tid < NB) atomicMax(&g_slots[t * NB + tid], best[tid]);
    __threadfence();

    __syncthreads();
    if (tid == 0) {
      const unsigned int old = atomicAdd(&g_tickets[t], 1u);
      flag = (old == gridDim.x - 1) ? 1 : 0;
    }
    __syncthreads();
    if (!flag) return;
    __threadfence();  // acquire all other blocks' slot updates
    if (tid < NB) {
      const unsigned long long pk = g_slots[t * NB + tid];
      const int tok = (int)(~(unsigned int)(pk & 0xFFFFFFFFull));
      out[tid * NT + t] = tok;
      toksh[tid] = tok;
    }
    __syncthreads();
    for (int i = tid; i < NB * NE; i += 256) {
      const int b = i & 63, e = i >> 6;
      const float v = emb[toksh[b] * NE + e];
      g_A[0][i] = v;  // x lives in both parity buffers
      g_A[1][i] = v;
    }
  } else {
    // Teacher-forced step: only block 0 does the (tiny) work.
    if (blockIdx.x != 0) return;
    if (tid < NB) {
      const int tok = input_x[tid * NT + t];
      out[tid * NT + t] = tok;
      toksh[tid] = tok;
    }
    __syncthreads();
    for (int i = tid; i < NB * NE; i += 256) {
      const int b = i & 63, e = i >> 6;
      const float v = emb[toksh[b] * NE + e];
      g_A[0][i] = v;
      g_A[1][i] = v;
    }
  }
}

// ---------------- host launch ----------------------------------------------
extern "C" void kernel_launch(void* const* d_in, const int* in_sizes, int n_in,
                              void* d_out, int out_size, void* d_ws, size_t ws_size,
                              hipStream_t stream) {
  const int* input_x = (const int*)d_in[0];
  const int* given_num = (const int*)d_in[1];
  const int* start_tok = (const int*)d_in[2];
  const float* emb = (const float*)d_in[3];
  const float* Wi = (const float*)d_in[4];
  const float* Ui = (const float*)d_in[5];
  const float* bi = (const float*)d_in[6];
  const float* Wf = (const float*)d_in[7];
  const float* Uf = (const float*)d_in[8];
  const float* bf = (const float*)d_in[9];
  const float* Wog = (const float*)d_in[10];
  const float* Uog = (const float*)d_in[11];
  const float* bog = (const float*)d_in[12];
  const float* Wc = (const float*)d_in[13];
  const float* Uc = (const float*)d_in[14];
  const float* bc = (const float*)d_in[15];
  const float* Wo = (const float*)d_in[16];
  const float* bo = (const float*)d_in[17];
  int* out = (int*)d_out;

  init_kernel<<<128, 256, 0, stream>>>(start_tok, emb);
  for (int t = 0; t < NT; ++t) {
    lstm_kernel<<<dim3(32, 4), 256, 0, stream>>>(t, Wi, Ui, Wf, Uf, Wog, Uog,
                                                 Wc, Uc, bi, bf, bog, bc);
    logits_kernel<<<313, 256, 0, stream>>>(t, input_x, given_num, emb, Wo, bo, out);
  }
}

// Round 4
// 2632.458 us; speedup vs baseline: 2.1287x; 2.1287x over previous
//
#include <hip/hip_runtime.h>
#include <stdint.h>

// Problem dims
constexpr int NB = 64;     // batch
constexpr int NT = 32;     // time steps
constexpr int NV = 10000;  // vocab
constexpr int NE = 256;    // embed
constexpr int NH = 512;    // hidden

#define PARTITIONABLE 1

// ---------------- persistent device state (re-inited every call) -----------
// g_A[p]: concatenated activations, [k][b] layout: k<NE -> x^T, k>=NE -> h^T
__device__ float g_A[2][(NE + NH) * NB];
__device__ float g_cT[2][NH * NB];
__device__ float g_part[4 * NB * NV];            // [kq][b][v] partial logits
__device__ unsigned int g_keys[2 * NT];          // per-step threefry keys
__device__ unsigned long long g_slots[NT * NB];  // packed argmax per (t,b)
__device__ unsigned int g_tickets[NT];           // fin last-block tickets

// ---------------- threefry2x32 (exact JAX semantics) -----------------------
__device__ __forceinline__ unsigned int rotl32(unsigned int x, int n) {
  return (x << n) | (x >> (32 - n));
}

__device__ __forceinline__ void threefry2x32(unsigned int k0, unsigned int k1,
                                             unsigned int x0, unsigned int x1,
                                             unsigned int& o0, unsigned int& o1) {
  unsigned int ks0 = k0, ks1 = k1, ks2 = k0 ^ k1 ^ 0x1BD11BDAu;
  const int R0[4] = {13, 15, 26, 6};
  const int R1[4] = {17, 29, 16, 24};
  x0 += ks0; x1 += ks1;
#pragma unroll
  for (int i = 0; i < 5; ++i) {
#pragma unroll
    for (int j = 0; j < 4; ++j) {
      const int r = ((i & 1) == 0) ? R0[j] : R1[j];
      x0 += x1; x1 = rotl32(x1, r); x1 ^= x0;
    }
    const unsigned int inj0 = (i == 0) ? ks1 : (i == 1) ? ks2 : (i == 2) ? ks0
                              : (i == 3) ? ks1 : ks2;
    const unsigned int inj1 = (i == 0) ? ks2 : (i == 1) ? ks0 : (i == 2) ? ks1
                              : (i == 3) ? ks2 : ks0;
    x0 += inj0;
    x1 += inj1 + (unsigned int)(i + 1);
  }
  o0 = x0; o1 = x1;
}

__device__ __forceinline__ float gumbel_from_bits(unsigned int bits) {
  float u = __uint_as_float((bits >> 9) | 0x3F800000u) - 1.0f;
  u = (u == 0.0f) ? 1.17549435e-38f : u;
  return -logf(-logf(u));
}

// ---------------- init: keys, state, x0, slots/tickets ---------------------
__global__ void init_kernel(const int* __restrict__ start_tok,
                            const float* __restrict__ emb) {
  const int gtid = blockIdx.x * blockDim.x + threadIdx.x;
  const int stride = gridDim.x * blockDim.x;
  if (gtid < NT) {
    unsigned int o0, o1;
#if PARTITIONABLE
    threefry2x32(0u, 42u, 0u, (unsigned int)gtid, o0, o1);
    g_keys[2 * gtid] = o0; g_keys[2 * gtid + 1] = o1;
#else
    threefry2x32(0u, 42u, (unsigned int)gtid, (unsigned int)(gtid + NT), o0, o1);
    g_keys[gtid] = o0; g_keys[gtid + NT] = o1;
#endif
  }
  for (int i = gtid; i < NT * NB; i += stride) g_slots[i] = 0ull;
  for (int i = gtid; i < NT; i += stride) g_tickets[i] = 0u;
  for (int i = gtid; i < NE * NB; i += stride) {
    const int b = i & 63, e = i >> 6;
    const float v = emb[start_tok[b] * NE + e];
    g_A[0][i] = v; g_A[1][i] = v;
  }
  for (int i = gtid; i < NH * NB; i += stride) {
    g_A[0][NE * NB + i] = 0.0f;
    g_cT[0][i] = 0.0f;
  }
}

// ---------------- LSTM: fully in-block (2 j-cols x 4 gates x 64 batch) -----
// grid 256: block bx covers j = {2bx, 2bx+1}. Wave = gate (tid>>6).
// Weight loads wave-uniform (broadcast); A loads coalesced 256B/wave,
// L1-shared by the 4 gate-waves. Gate exchange via 2KB LDS; activation
// in-block; no global preact, no tickets, no fences.
__global__ __launch_bounds__(256) void lstm_kernel(
    int t,
    const float* __restrict__ Wi, const float* __restrict__ Ui,
    const float* __restrict__ Wf, const float* __restrict__ Uf,
    const float* __restrict__ Wog, const float* __restrict__ Uog,
    const float* __restrict__ Wc, const float* __restrict__ Uc,
    const float* __restrict__ bi, const float* __restrict__ bf,
    const float* __restrict__ bog, const float* __restrict__ bc) {
  const int tid = threadIdx.x;
  const int g = tid >> 6;
  const int b = tid & 63;
  const int j0 = blockIdx.x * 2;
  const float* W = (g == 0) ? Wi : (g == 1) ? Wf : (g == 2) ? Wog : Wc;
  const float* U = (g == 0) ? Ui : (g == 1) ? Uf : (g == 2) ? Uog : Uc;
  const float* A = g_A[t & 1];

  float acc0 = 0.f, acc1 = 0.f;
#pragma unroll 8
  for (int k = 0; k < NE; ++k) {
    const float av = A[k * NB + b];
    const float2 wv = *(const float2*)(W + k * NH + j0);
    acc0 = fmaf(av, wv.x, acc0);
    acc1 = fmaf(av, wv.y, acc1);
  }
#pragma unroll 8
  for (int k = 0; k < NH; ++k) {
    const float av = A[(NE + k) * NB + b];
    const float2 wv = *(const float2*)(U + k * NH + j0);
    acc0 = fmaf(av, wv.x, acc0);
    acc1 = fmaf(av, wv.y, acc1);
  }

  __shared__ float zsh[4][2][NB];
  zsh[g][0][b] = acc0;
  zsh[g][1][b] = acc1;
  __syncthreads();
  if (tid < 128) {
    const int jj = tid >> 6;
    const int bb = tid & 63;
    const int col = j0 + jj;
    const int idx = col * NB + bb;
    const float zi = zsh[0][jj][bb] + bi[col];
    const float zf = zsh[1][jj][bb] + bf[col];
    const float zo = zsh[2][jj][bb] + bog[col];
    const float zc = zsh[3][jj][bb] + bc[col];
    const float iv = 1.0f / (1.0f + expf(-zi));
    const float fv = 1.0f / (1.0f + expf(-zf));
    const float ov = 1.0f / (1.0f + expf(-zo));
    const float cc = tanhf(zc);
    const float cold = g_cT[t & 1][idx];
    const float cn = fv * cold + iv * cc;
    g_cT[(t & 1) ^ 1][idx] = cn;
    g_A[(t & 1) ^ 1][NE * NB + idx] = ov * tanhf(cn);
  }
}

// ---------------- logits partials: K split across blocks -------------------
// grid (313, 4): x = 32-vocab tile, y = 128-K chunk. Thread: 4 vocab
// (float4 Wo) x 2 batch (float2 LDS h). Flat unrolled loop, NO register
// arrays (round-3 spill lesson). Wo element read exactly once per step.
__global__ __launch_bounds__(256) void logits_part_kernel(
    int t, const int* __restrict__ given_p, const float* __restrict__ Wo) {
  const int given = *given_p;
  if (t < given) return;
  __shared__ float hs[128 * NB];  // 32 KB K-chunk of h
  const int tid = threadIdx.x;
  const int kq = blockIdx.y;
  const int vq = tid & 7;
  const int bl0 = (tid >> 3) * 2;
  const int n = blockIdx.x * 32 + vq * 4;
  const bool nv = (n < NV);
  const int nl = nv ? n : 0;

  const float* hT = g_A[(t & 1) ^ 1] + NE * NB;
  {
    const float4* src = (const float4*)(hT + kq * 128 * NB);
    float4* dst = (float4*)hs;
#pragma unroll
    for (int i = 0; i < 8; ++i) dst[tid + i * 256] = src[tid + i * 256];
  }
  __syncthreads();

  float a00 = 0.f, a01 = 0.f, a02 = 0.f, a03 = 0.f;
  float a10 = 0.f, a11 = 0.f, a12 = 0.f, a13 = 0.f;
  const float* wpc = Wo + (size_t)kq * 128 * NV + nl;
#pragma unroll 8
  for (int kk = 0; kk < 128; ++kk) {
    const float4 w = *(const float4*)(wpc + (size_t)kk * NV);
    const float2 h2 = *(const float2*)(hs + kk * NB + bl0);
    a00 = fmaf(h2.x, w.x, a00); a01 = fmaf(h2.x, w.y, a01);
    a02 = fmaf(h2.x, w.z, a02); a03 = fmaf(h2.x, w.w, a03);
    a10 = fmaf(h2.y, w.x, a10); a11 = fmaf(h2.y, w.y, a11);
    a12 = fmaf(h2.y, w.z, a12); a13 = fmaf(h2.y, w.w, a13);
  }
  if (nv) {
    float4 r0; r0.x = a00; r0.y = a01; r0.z = a02; r0.w = a03;
    float4 r1; r1.x = a10; r1.y = a11; r1.z = a12; r1.w = a13;
    *(float4*)(g_part + (size_t)(kq * NB + bl0) * NV + n) = r0;
    *(float4*)(g_part + (size_t)(kq * NB + bl0 + 1) * NV + n) = r1;
  }
}

// ---------------- logits finalize: reduce + gumbel + argmax + token --------
// grid (313): same (vq, bl0) mapping as part. Fixed reduce order
// ((p0+p1)+p2)+p3 + bo. Last block (ticket) writes tokens + gathers x_{t+1}.
__global__ __launch_bounds__(256) void logits_fin_kernel(
    int t, const int* __restrict__ input_x, const int* __restrict__ given_p,
    const float* __restrict__ emb, const float* __restrict__ bo,
    int* __restrict__ out) {
  __shared__ unsigned long long best[NB];
  __shared__ int toksh[NB];
  __shared__ int flag;
  const int tid = threadIdx.x;
  const int given = *given_p;

  if (t >= given) {
    const int vq = tid & 7;
    const int bl0 = (tid >> 3) * 2;
    const int n = blockIdx.x * 32 + vq * 4;
    const bool nv = (n < NV);
    const int nl = nv ? n : 0;
    if (tid < NB) best[tid] = 0ull;
    __syncthreads();

    if (nv) {
      const unsigned int key0 = g_keys[2 * t], key1 = g_keys[2 * t + 1];
      const float4 bo4 = *(const float4*)(bo + nl);
#pragma unroll
      for (int s = 0; s < 2; ++s) {
        const int bg = bl0 + s;
        const float4 p0 = *(const float4*)(g_part + (size_t)(0 * NB + bg) * NV + n);
        const float4 p1 = *(const float4*)(g_part + (size_t)(1 * NB + bg) * NV + n);
        const float4 p2 = *(const float4*)(g_part + (size_t)(2 * NB + bg) * NV + n);
        const float4 p3 = *(const float4*)(g_part + (size_t)(3 * NB + bg) * NV + n);
        float lg[4];
        lg[0] = ((p0.x + p1.x) + p2.x) + p3.x + bo4.x;
        lg[1] = ((p0.y + p1.y) + p2.y) + p3.y + bo4.y;
        lg[2] = ((p0.z + p1.z) + p2.z) + p3.z + bo4.z;
        lg[3] = ((p0.w + p1.w) + p2.w) + p3.w + bo4.w;
        unsigned long long bp = 0ull;
#pragma unroll
        for (int jj = 0; jj < 4; ++jj) {
          const int v = n + jj;
          unsigned int u0, u1, bits;
#if PARTITIONABLE
          threefry2x32(key0, key1, 0u, (unsigned int)(bg * NV + v), u0, u1);
          bits = u0 ^ u1;
#else
          const int p = bg * NV + v;
          const unsigned int c = (unsigned int)(p >= (NB / 2) * NV ? p - (NB / 2) * NV : p);
          threefry2x32(key0, key1, c, c + (unsigned int)((NB / 2) * NV), u0, u1);
          bits = (p >= (NB / 2) * NV) ? u1 : u0;
#endif
          const float val = gumbel_from_bits(bits) + lg[jj];
          const unsigned int fb = __float_as_uint(val);
          const unsigned int ord = (fb & 0x80000000u) ? ~fb : (fb | 0x80000000u);
          const unsigned long long pk =
              ((unsigned long long)ord << 32) | (unsigned int)(~v);
          bp = (pk > bp) ? pk : bp;
        }
        atomicMax(&best[bg], bp);
      }
    }
    __syncthreads();
    if (tid < NB) atomicMax(&g_slots[t * NB + tid], best[tid]);
    __threadfence();

    __syncthreads();
    if (tid == 0) {
      const unsigned int old = atomicAdd(&g_tickets[t], 1u);
      flag = (old == gridDim.x - 1) ? 1 : 0;
    }
    __syncthreads();
    if (!flag) return;
    __threadfence();  // acquire all other blocks' slot updates
    if (tid < NB) {
      const unsigned long long pk = g_slots[t * NB + tid];
      const int tok = (int)(~(unsigned int)(pk & 0xFFFFFFFFull));
      out[tid * NT + t] = tok;
      toksh[tid] = tok;
    }
    __syncthreads();
    for (int i = tid; i < NB * NE; i += 256) {
      const int b = i & 63, e = i >> 6;
      const float v = emb[toksh[b] * NE + e];
      g_A[0][i] = v;  // x lives in both parity buffers
      g_A[1][i] = v;
    }
  } else {
    // Teacher-forced step: only block 0 does the (tiny) work.
    if (blockIdx.x != 0) return;
    if (tid < NB) {
      const int tok = input_x[tid * NT + t];
      out[tid * NT + t] = tok;
      toksh[tid] = tok;
    }
    __syncthreads();
    for (int i = tid; i < NB * NE; i += 256) {
      const int b = i & 63, e = i >> 6;
      const float v = emb[toksh[b] * NE + e];
      g_A[0][i] = v;
      g_A[1][i] = v;
    }
  }
}

// ---------------- host launch ----------------------------------------------
extern "C" void kernel_launch(void* const* d_in, const int* in_sizes, int n_in,
                              void* d_out, int out_size, void* d_ws, size_t ws_size,
                              hipStream_t stream) {
  const int* input_x = (const int*)d_in[0];
  const int* given_num = (const int*)d_in[1];
  const int* start_tok = (const int*)d_in[2];
  const float* emb = (const float*)d_in[3];
  const float* Wi = (const float*)d_in[4];
  const float* Ui = (const float*)d_in[5];
  const float* bi = (const float*)d_in[6];
  const float* Wf = (const float*)d_in[7];
  const float* Uf = (const float*)d_in[8];
  const float* bf = (const float*)d_in[9];
  const float* Wog = (const float*)d_in[10];
  const float* Uog = (const float*)d_in[11];
  const float* bog = (const float*)d_in[12];
  const float* Wc = (const float*)d_in[13];
  const float* Uc = (const float*)d_in[14];
  const float* bc = (const float*)d_in[15];
  const float* Wo = (const float*)d_in[16];
  const float* bo = (const float*)d_in[17];
  int* out = (int*)d_out;

  init_kernel<<<128, 256, 0, stream>>>(start_tok, emb);
  for (int t = 0; t < NT; ++t) {
    lstm_kernel<<<256, 256, 0, stream>>>(t, Wi, Ui, Wf, Uf, Wog, Uog,
                                         Wc, Uc, bi, bf, bog, bc);
    logits_part_kernel<<<dim3(313, 4), 256, 0, stream>>>(t, given_num, Wo);
    logits_fin_kernel<<<313, 256, 0, stream>>>(t, input_x, given_num, emb, bo, out);
  }
}

// Round 5
// 1775.823 us; speedup vs baseline: 3.1556x; 1.4824x over previous
//
#include <hip/hip_runtime.h>
#include <stdint.h>

// Problem dims
constexpr int NB = 64;     // batch
constexpr int NT = 32;     // time steps
constexpr int NV = 10000;  // vocab
constexpr int NE = 256;    // embed
constexpr int NH = 512;    // hidden

#define PARTITIONABLE 1

// ---------------- persistent device state (re-inited every call) -----------
// g_A[p]: concatenated activations, [k][b] layout: k<NE -> x^T, k>=NE -> h^T
__device__ float g_A[2][(NE + NH) * NB];
__device__ float g_cT[2][NH * NB];
__device__ float g_part[4 * NB * NV];            // [kq][b][v] logits partials
__device__ float g_lp[16 * NH * NB];             // [kq][gate][j][b] lstm partials
__device__ unsigned int g_keys[2 * NT];          // per-step threefry keys
__device__ unsigned long long g_slots[NT * NB];  // packed argmax per (t,b)
__device__ unsigned int g_tickets[NT];           // fin last-block tickets

// ---------------- threefry2x32 (exact JAX semantics) -----------------------
__device__ __forceinline__ unsigned int rotl32(unsigned int x, int n) {
  return (x << n) | (x >> (32 - n));
}

__device__ __forceinline__ void threefry2x32(unsigned int k0, unsigned int k1,
                                             unsigned int x0, unsigned int x1,
                                             unsigned int& o0, unsigned int& o1) {
  unsigned int ks0 = k0, ks1 = k1, ks2 = k0 ^ k1 ^ 0x1BD11BDAu;
  const int R0[4] = {13, 15, 26, 6};
  const int R1[4] = {17, 29, 16, 24};
  x0 += ks0; x1 += ks1;
#pragma unroll
  for (int i = 0; i < 5; ++i) {
#pragma unroll
    for (int j = 0; j < 4; ++j) {
      const int r = ((i & 1) == 0) ? R0[j] : R1[j];
      x0 += x1; x1 = rotl32(x1, r); x1 ^= x0;
    }
    const unsigned int inj0 = (i == 0) ? ks1 : (i == 1) ? ks2 : (i == 2) ? ks0
                              : (i == 3) ? ks1 : ks2;
    const unsigned int inj1 = (i == 0) ? ks2 : (i == 1) ? ks0 : (i == 2) ? ks1
                              : (i == 3) ? ks2 : ks0;
    x0 += inj0;
    x1 += inj1 + (unsigned int)(i + 1);
  }
  o0 = x0; o1 = x1;
}

__device__ __forceinline__ float gumbel_from_bits(unsigned int bits) {
  float u = __uint_as_float((bits >> 9) | 0x3F800000u) - 1.0f;
  u = (u == 0.0f) ? 1.17549435e-38f : u;
  return -logf(-logf(u));
}

// ---------------- init: keys, state, x0, slots/tickets ---------------------
__global__ void init_kernel(const int* __restrict__ start_tok,
                            const float* __restrict__ emb) {
  const int gtid = blockIdx.x * blockDim.x + threadIdx.x;
  const int stride = gridDim.x * blockDim.x;
  if (gtid < NT) {
    unsigned int o0, o1;
#if PARTITIONABLE
    threefry2x32(0u, 42u, 0u, (unsigned int)gtid, o0, o1);
    g_keys[2 * gtid] = o0; g_keys[2 * gtid + 1] = o1;
#else
    threefry2x32(0u, 42u, (unsigned int)gtid, (unsigned int)(gtid + NT), o0, o1);
    g_keys[gtid] = o0; g_keys[gtid + NT] = o1;
#endif
  }
  for (int i = gtid; i < NT * NB; i += stride) g_slots[i] = 0ull;
  for (int i = gtid; i < NT; i += stride) g_tickets[i] = 0u;
  for (int i = gtid; i < NE * NB; i += stride) {
    const int b = i & 63, e = i >> 6;
    const float v = emb[start_tok[b] * NE + e];
    g_A[0][i] = v; g_A[1][i] = v;
  }
  for (int i = gtid; i < NH * NB; i += stride) {
    g_A[0][NE * NB + i] = 0.0f;
    g_cT[0][i] = 0.0f;
  }
}

// ---------------- LSTM partials: j x gate x K-chunk ------------------------
// grid (16, 4, 4): x = 32-wide j tile, y = gate, z = 192-row K chunk.
// Thread: 4 j (per-lane float4 weight load -> vector, not scalar) x 2 batch.
// A chunk staged in 48 KB LDS. Chunk boundaries match rounds 1-3 q-split.
__global__ __launch_bounds__(256) void lstm_part_kernel(
    int t,
    const float* __restrict__ Wi, const float* __restrict__ Ui,
    const float* __restrict__ Wf, const float* __restrict__ Uf,
    const float* __restrict__ Wog, const float* __restrict__ Uog,
    const float* __restrict__ Wc, const float* __restrict__ Uc) {
  __shared__ float as_[192 * NB];  // 48 KB chunk of A
  const int tid = threadIdx.x;
  const int vq = tid & 7;
  const int bl0 = (tid >> 3) * 2;
  const int jx = blockIdx.x;
  const int g = blockIdx.y;
  const int q = blockIdx.z;
  const int j = jx * 32 + vq * 4;
  const float* W = (g == 0) ? Wi : (g == 1) ? Wf : (g == 2) ? Wog : Wc;
  const float* U = (g == 0) ? Ui : (g == 1) ? Uf : (g == 2) ? Uog : Uc;
  const float* A = g_A[t & 1];

  {
    const float4* src = (const float4*)(A + q * 192 * NB);
    float4* dst = (float4*)as_;
#pragma unroll
    for (int i = 0; i < 12; ++i) dst[tid + i * 256] = src[tid + i * 256];
  }
  __syncthreads();

  const int r0 = q * 192, r1 = r0 + 192;
  float a00 = 0.f, a01 = 0.f, a02 = 0.f, a03 = 0.f;
  float a10 = 0.f, a11 = 0.f, a12 = 0.f, a13 = 0.f;

  // W rows: [r0, min(r1, NE))
  const int we = (r1 < NE) ? r1 : NE;
#pragma unroll 8
  for (int k = r0; k < we; ++k) {
    const float4 w = *(const float4*)(W + k * NH + j);
    const float2 h2 = *(const float2*)(as_ + (k - r0) * NB + bl0);
    a00 = fmaf(h2.x, w.x, a00); a01 = fmaf(h2.x, w.y, a01);
    a02 = fmaf(h2.x, w.z, a02); a03 = fmaf(h2.x, w.w, a03);
    a10 = fmaf(h2.y, w.x, a10); a11 = fmaf(h2.y, w.y, a11);
    a12 = fmaf(h2.y, w.z, a12); a13 = fmaf(h2.y, w.w, a13);
  }
  // U rows: [max(r0, NE), r1)
  const int us = (r0 > NE) ? r0 : NE;
#pragma unroll 8
  for (int k = us; k < r1; ++k) {
    const float4 w = *(const float4*)(U + (k - NE) * NH + j);
    const float2 h2 = *(const float2*)(as_ + (k - r0) * NB + bl0);
    a00 = fmaf(h2.x, w.x, a00); a01 = fmaf(h2.x, w.y, a01);
    a02 = fmaf(h2.x, w.z, a02); a03 = fmaf(h2.x, w.w, a03);
    a10 = fmaf(h2.y, w.x, a10); a11 = fmaf(h2.y, w.y, a11);
    a12 = fmaf(h2.y, w.z, a12); a13 = fmaf(h2.y, w.w, a13);
  }

  const size_t base = ((size_t)(q * 4 + g) * NH + j) * NB + bl0;
  float2 s0; s0.x = a00; s0.y = a10;
  float2 s1; s1.x = a01; s1.y = a11;
  float2 s2; s2.x = a02; s2.y = a12;
  float2 s3; s3.x = a03; s3.y = a13;
  *(float2*)(g_lp + base + 0 * NB) = s0;
  *(float2*)(g_lp + base + 1 * NB) = s1;
  *(float2*)(g_lp + base + 2 * NB) = s2;
  *(float2*)(g_lp + base + 3 * NB) = s3;
}

// ---------------- LSTM finalize: reduce + bias + gating + state ------------
// grid 128: thread = one (j, b). Reduce ((q0+q1)+q2)+q3 per gate (matches
// rounds 1-3 order), then sigmoid/tanh + c/h update.
__global__ __launch_bounds__(256) void lstm_fin_kernel(
    int t, const float* __restrict__ bi, const float* __restrict__ bf,
    const float* __restrict__ bog, const float* __restrict__ bc) {
  const int flat = blockIdx.x * 256 + threadIdx.x;  // j*64 + b
  const int j = flat >> 6;
  float z[4];
#pragma unroll
  for (int g = 0; g < 4; ++g) {
    const float p0 = g_lp[(size_t)(0 * 4 + g) * NH * NB + flat];
    const float p1 = g_lp[(size_t)(1 * 4 + g) * NH * NB + flat];
    const float p2 = g_lp[(size_t)(2 * 4 + g) * NH * NB + flat];
    const float p3 = g_lp[(size_t)(3 * 4 + g) * NH * NB + flat];
    z[g] = ((p0 + p1) + p2) + p3;
  }
  const float zi = z[0] + bi[j];
  const float zf = z[1] + bf[j];
  const float zo = z[2] + bog[j];
  const float zc = z[3] + bc[j];
  const float iv = 1.0f / (1.0f + expf(-zi));
  const float fv = 1.0f / (1.0f + expf(-zf));
  const float ov = 1.0f / (1.0f + expf(-zo));
  const float cc = tanhf(zc);
  const float cold = g_cT[t & 1][flat];
  const float cn = fv * cold + iv * cc;
  g_cT[(t & 1) ^ 1][flat] = cn;
  g_A[(t & 1) ^ 1][NE * NB + flat] = ov * tanhf(cn);
}

// ---------------- logits partials: K split across blocks -------------------
// grid (313, 4): x = 32-vocab tile, y = 128-K chunk. Thread: 4 vocab
// (float4 Wo) x 2 batch (float2 LDS h). Flat unrolled loop, NO register
// arrays (round-3 spill lesson). Wo element read exactly once per step.
__global__ __launch_bounds__(256) void logits_part_kernel(
    int t, const int* __restrict__ given_p, const float* __restrict__ Wo) {
  const int given = *given_p;
  if (t < given) return;
  __shared__ float hs[128 * NB];  // 32 KB K-chunk of h
  const int tid = threadIdx.x;
  const int kq = blockIdx.y;
  const int vq = tid & 7;
  const int bl0 = (tid >> 3) * 2;
  const int n = blockIdx.x * 32 + vq * 4;
  const bool nv = (n < NV);
  const int nl = nv ? n : 0;

  const float* hT = g_A[(t & 1) ^ 1] + NE * NB;
  {
    const float4* src = (const float4*)(hT + kq * 128 * NB);
    float4* dst = (float4*)hs;
#pragma unroll
    for (int i = 0; i < 8; ++i) dst[tid + i * 256] = src[tid + i * 256];
  }
  __syncthreads();

  float a00 = 0.f, a01 = 0.f, a02 = 0.f, a03 = 0.f;
  float a10 = 0.f, a11 = 0.f, a12 = 0.f, a13 = 0.f;
  const float* wpc = Wo + (size_t)kq * 128 * NV + nl;
#pragma unroll 8
  for (int kk = 0; kk < 128; ++kk) {
    const float4 w = *(const float4*)(wpc + (size_t)kk * NV);
    const float2 h2 = *(const float2*)(hs + kk * NB + bl0);
    a00 = fmaf(h2.x, w.x, a00); a01 = fmaf(h2.x, w.y, a01);
    a02 = fmaf(h2.x, w.z, a02); a03 = fmaf(h2.x, w.w, a03);
    a10 = fmaf(h2.y, w.x, a10); a11 = fmaf(h2.y, w.y, a11);
    a12 = fmaf(h2.y, w.z, a12); a13 = fmaf(h2.y, w.w, a13);
  }
  if (nv) {
    float4 r0; r0.x = a00; r0.y = a01; r0.z = a02; r0.w = a03;
    float4 r1; r1.x = a10; r1.y = a11; r1.z = a12; r1.w = a13;
    *(float4*)(g_part + (size_t)(kq * NB + bl0) * NV + n) = r0;
    *(float4*)(g_part + (size_t)(kq * NB + bl0 + 1) * NV + n) = r1;
  }
}

// ---------------- logits finalize: reduce + gumbel + argmax + token --------
// grid (313): same (vq, bl0) mapping as part. Fixed reduce order
// ((p0+p1)+p2)+p3 + bo. Last block (ticket) writes tokens + gathers x_{t+1}.
__global__ __launch_bounds__(256) void logits_fin_kernel(
    int t, const int* __restrict__ input_x, const int* __restrict__ given_p,
    const float* __restrict__ emb, const float* __restrict__ bo,
    int* __restrict__ out) {
  __shared__ unsigned long long best[NB];
  __shared__ int toksh[NB];
  __shared__ int flag;
  const int tid = threadIdx.x;
  const int given = *given_p;

  if (t >= given) {
    const int vq = tid & 7;
    const int bl0 = (tid >> 3) * 2;
    const int n = blockIdx.x * 32 + vq * 4;
    const bool nv = (n < NV);
    const int nl = nv ? n : 0;
    if (tid < NB) best[tid] = 0ull;
    __syncthreads();

    if (nv) {
      const unsigned int key0 = g_keys[2 * t], key1 = g_keys[2 * t + 1];
      const float4 bo4 = *(const float4*)(bo + nl);
#pragma unroll
      for (int s = 0; s < 2; ++s) {
        const int bg = bl0 + s;
        const float4 p0 = *(const float4*)(g_part + (size_t)(0 * NB + bg) * NV + n);
        const float4 p1 = *(const float4*)(g_part + (size_t)(1 * NB + bg) * NV + n);
        const float4 p2 = *(const float4*)(g_part + (size_t)(2 * NB + bg) * NV + n);
        const float4 p3 = *(const float4*)(g_part + (size_t)(3 * NB + bg) * NV + n);
        float lg[4];
        lg[0] = ((p0.x + p1.x) + p2.x) + p3.x + bo4.x;
        lg[1] = ((p0.y + p1.y) + p2.y) + p3.y + bo4.y;
        lg[2] = ((p0.z + p1.z) + p2.z) + p3.z + bo4.z;
        lg[3] = ((p0.w + p1.w) + p2.w) + p3.w + bo4.w;
        unsigned long long bp = 0ull;
#pragma unroll
        for (int jj = 0; jj < 4; ++jj) {
          const int v = n + jj;
          unsigned int u0, u1, bits;
#if PARTITIONABLE
          threefry2x32(key0, key1, 0u, (unsigned int)(bg * NV + v), u0, u1);
          bits = u0 ^ u1;
#else
          const int p = bg * NV + v;
          const unsigned int c = (unsigned int)(p >= (NB / 2) * NV ? p - (NB / 2) * NV : p);
          threefry2x32(key0, key1, c, c + (unsigned int)((NB / 2) * NV), u0, u1);
          bits = (p >= (NB / 2) * NV) ? u1 : u0;
#endif
          const float val = gumbel_from_bits(bits) + lg[jj];
          const unsigned int fb = __float_as_uint(val);
          const unsigned int ord = (fb & 0x80000000u) ? ~fb : (fb | 0x80000000u);
          const unsigned long long pk =
              ((unsigned long long)ord << 32) | (unsigned int)(~v);
          bp = (pk > bp) ? pk : bp;
        }
        atomicMax(&best[bg], bp);
      }
    }
    __syncthreads();
    if (tid < NB) atomicMax(&g_slots[t * NB + tid], best[tid]);
    __threadfence();

    __syncthreads();
    if (tid == 0) {
      const unsigned int old = atomicAdd(&g_tickets[t], 1u);
      flag = (old == gridDim.x - 1) ? 1 : 0;
    }
    __syncthreads();
    if (!flag) return;
    __threadfence();  // acquire all other blocks' slot updates
    if (tid < NB) {
      const unsigned long long pk = g_slots[t * NB + tid];
      const int tok = (int)(~(unsigned int)(pk & 0xFFFFFFFFull));
      out[tid * NT + t] = tok;
      toksh[tid] = tok;
    }
    __syncthreads();
    for (int i = tid; i < NB * NE; i += 256) {
      const int b = i & 63, e = i >> 6;
      const float v = emb[toksh[b] * NE + e];
      g_A[0][i] = v;  // x lives in both parity buffers
      g_A[1][i] = v;
    }
  } else {
    // Teacher-forced step: only block 0 does the (tiny) work.
    if (blockIdx.x != 0) return;
    if (tid < NB) {
      const int tok = input_x[tid * NT + t];
      out[tid * NT + t] = tok;
      toksh[tid] = tok;
    }
    __syncthreads();
    for (int i = tid; i < NB * NE; i += 256) {
      const int b = i & 63, e = i >> 6;
      const float v = emb[toksh[b] * NE + e];
      g_A[0][i] = v;
      g_A[1][i] = v;
    }
  }
}

// ---------------- host launch ----------------------------------------------
extern "C" void kernel_launch(void* const* d_in, const int* in_sizes, int n_in,
                              void* d_out, int out_size, void* d_ws, size_t ws_size,
                              hipStream_t stream) {
  const int* input_x = (const int*)d_in[0];
  const int* given_num = (const int*)d_in[1];
  const int* start_tok = (const int*)d_in[2];
  const float* emb = (const float*)d_in[3];
  const float* Wi = (const float*)d_in[4];
  const float* Ui = (const float*)d_in[5];
  const float* bi = (const float*)d_in[6];
  const float* Wf = (const float*)d_in[7];
  const float* Uf = (const float*)d_in[8];
  const float* bf = (const float*)d_in[9];
  const float* Wog = (const float*)d_in[10];
  const float* Uog = (const float*)d_in[11];
  const float* bog = (const float*)d_in[12];
  const float* Wc = (const float*)d_in[13];
  const float* Uc = (const float*)d_in[14];
  const float* bc = (const float*)d_in[15];
  const float* Wo = (const float*)d_in[16];
  const float* bo = (const float*)d_in[17];
  int* out = (int*)d_out;

  init_kernel<<<128, 256, 0, stream>>>(start_tok, emb);
  for (int t = 0; t < NT; ++t) {
    lstm_part_kernel<<<dim3(16, 4, 4), 256, 0, stream>>>(t, Wi, Ui, Wf, Uf,
                                                         Wog, Uog, Wc, Uc);
    lstm_fin_kernel<<<128, 256, 0, stream>>>(t, bi, bf, bog, bc);
    logits_part_kernel<<<dim3(313, 4), 256, 0, stream>>>(t, given_num, Wo);
    logits_fin_kernel<<<313, 256, 0, stream>>>(t, input_x, given_num, emb, bo, out);
  }
}

// Round 6
// 1366.260 us; speedup vs baseline: 4.1015x; 1.2998x over previous
//
#include <hip/hip_runtime.h>
#include <stdint.h>

// Problem dims
constexpr int NB = 64;     // batch
constexpr int NT = 32;     // time steps
constexpr int NV = 10000;  // vocab
constexpr int NE = 256;    // embed
constexpr int NH = 512;    // hidden

#define PARTITIONABLE 1

// ---------------- persistent device state (re-inited every call) -----------
// g_A[p]: concatenated activations, [k][b] layout: k<NE -> x^T, k>=NE -> h^T
__device__ float g_A[2][(NE + NH) * NB];
__device__ float g_cT[2][NH * NB];
__device__ float g_part[4 * NB * NV];            // [kq][b][v] logits partials
__device__ float g_lp[16 * NH * NB];             // [kq][gate][j][b] lstm partials
__device__ unsigned int g_keys[2 * NT];          // per-step threefry keys
__device__ unsigned long long g_slots[NT * NB];  // packed argmax per (t,b)

// ---------------- threefry2x32 (exact JAX semantics) -----------------------
__device__ __forceinline__ unsigned int rotl32(unsigned int x, int n) {
  return (x << n) | (x >> (32 - n));
}

__device__ __forceinline__ void threefry2x32(unsigned int k0, unsigned int k1,
                                             unsigned int x0, unsigned int x1,
                                             unsigned int& o0, unsigned int& o1) {
  unsigned int ks0 = k0, ks1 = k1, ks2 = k0 ^ k1 ^ 0x1BD11BDAu;
  const int R0[4] = {13, 15, 26, 6};
  const int R1[4] = {17, 29, 16, 24};
  x0 += ks0; x1 += ks1;
#pragma unroll
  for (int i = 0; i < 5; ++i) {
#pragma unroll
    for (int j = 0; j < 4; ++j) {
      const int r = ((i & 1) == 0) ? R0[j] : R1[j];
      x0 += x1; x1 = rotl32(x1, r); x1 ^= x0;
    }
    const unsigned int inj0 = (i == 0) ? ks1 : (i == 1) ? ks2 : (i == 2) ? ks0
                              : (i == 3) ? ks1 : ks2;
    const unsigned int inj1 = (i == 0) ? ks2 : (i == 1) ? ks0 : (i == 2) ? ks1
                              : (i == 3) ? ks2 : ks0;
    x0 += inj0;
    x1 += inj1 + (unsigned int)(i + 1);
  }
  o0 = x0; o1 = x1;
}

__device__ __forceinline__ float gumbel_from_bits(unsigned int bits) {
  float u = __uint_as_float((bits >> 9) | 0x3F800000u) - 1.0f;
  u = (u == 0.0f) ? 1.17549435e-38f : u;
  return -logf(-logf(u));
}

// ---------------- init: keys, state, x0, slots -----------------------------
__global__ void init_kernel(const int* __restrict__ start_tok,
                            const float* __restrict__ emb) {
  const int gtid = blockIdx.x * blockDim.x + threadIdx.x;
  const int stride = gridDim.x * blockDim.x;
  if (gtid < NT) {
    unsigned int o0, o1;
#if PARTITIONABLE
    threefry2x32(0u, 42u, 0u, (unsigned int)gtid, o0, o1);
    g_keys[2 * gtid] = o0; g_keys[2 * gtid + 1] = o1;
#else
    threefry2x32(0u, 42u, (unsigned int)gtid, (unsigned int)(gtid + NT), o0, o1);
    g_keys[gtid] = o0; g_keys[gtid + NT] = o1;
#endif
  }
  for (int i = gtid; i < NT * NB; i += stride) g_slots[i] = 0ull;
  for (int i = gtid; i < NE * NB; i += stride) {
    const int b = i & 63, e = i >> 6;
    g_A[0][i] = emb[start_tok[b] * NE + e];  // step 0 reads buffer 0
  }
  for (int i = gtid; i < NH * NB; i += stride) {
    g_A[0][NE * NB + i] = 0.0f;
    g_cT[0][i] = 0.0f;
  }
}

// ---------------- LSTM partials: j x gate x K-chunk ------------------------
// grid (16, 4, 4): x = 32-wide j tile, y = gate, z = 192-row K chunk.
// Thread: 4 j (per-lane float4 weight load) x 2 batch. A chunk in 48 KB LDS.
__global__ __launch_bounds__(256) void lstm_part_kernel(
    int t,
    const float* __restrict__ Wi, const float* __restrict__ Ui,
    const float* __restrict__ Wf, const float* __restrict__ Uf,
    const float* __restrict__ Wog, const float* __restrict__ Uog,
    const float* __restrict__ Wc, const float* __restrict__ Uc) {
  __shared__ float as_[192 * NB];  // 48 KB chunk of A
  const int tid = threadIdx.x;
  const int vq = tid & 7;
  const int bl0 = (tid >> 3) * 2;
  const int jx = blockIdx.x;
  const int g = blockIdx.y;
  const int q = blockIdx.z;
  const int j = jx * 32 + vq * 4;
  const float* W = (g == 0) ? Wi : (g == 1) ? Wf : (g == 2) ? Wog : Wc;
  const float* U = (g == 0) ? Ui : (g == 1) ? Uf : (g == 2) ? Uog : Uc;
  const float* A = g_A[t & 1];

  {
    const float4* src = (const float4*)(A + q * 192 * NB);
    float4* dst = (float4*)as_;
#pragma unroll
    for (int i = 0; i < 12; ++i) dst[tid + i * 256] = src[tid + i * 256];
  }
  __syncthreads();

  const int r0 = q * 192, r1 = r0 + 192;
  float a00 = 0.f, a01 = 0.f, a02 = 0.f, a03 = 0.f;
  float a10 = 0.f, a11 = 0.f, a12 = 0.f, a13 = 0.f;

  // W rows: [r0, min(r1, NE))
  const int we = (r1 < NE) ? r1 : NE;
#pragma unroll 8
  for (int k = r0; k < we; ++k) {
    const float4 w = *(const float4*)(W + k * NH + j);
    const float2 h2 = *(const float2*)(as_ + (k - r0) * NB + bl0);
    a00 = fmaf(h2.x, w.x, a00); a01 = fmaf(h2.x, w.y, a01);
    a02 = fmaf(h2.x, w.z, a02); a03 = fmaf(h2.x, w.w, a03);
    a10 = fmaf(h2.y, w.x, a10); a11 = fmaf(h2.y, w.y, a11);
    a12 = fmaf(h2.y, w.z, a12); a13 = fmaf(h2.y, w.w, a13);
  }
  // U rows: [max(r0, NE), r1)
  const int us = (r0 > NE) ? r0 : NE;
#pragma unroll 8
  for (int k = us; k < r1; ++k) {
    const float4 w = *(const float4*)(U + (k - NE) * NH + j);
    const float2 h2 = *(const float2*)(as_ + (k - r0) * NB + bl0);
    a00 = fmaf(h2.x, w.x, a00); a01 = fmaf(h2.x, w.y, a01);
    a02 = fmaf(h2.x, w.z, a02); a03 = fmaf(h2.x, w.w, a03);
    a10 = fmaf(h2.y, w.x, a10); a11 = fmaf(h2.y, w.y, a11);
    a12 = fmaf(h2.y, w.z, a12); a13 = fmaf(h2.y, w.w, a13);
  }

  const size_t base = ((size_t)(q * 4 + g) * NH + j) * NB + bl0;
  float2 s0; s0.x = a00; s0.y = a10;
  float2 s1; s1.x = a01; s1.y = a11;
  float2 s2; s2.x = a02; s2.y = a12;
  float2 s3; s3.x = a03; s3.y = a13;
  *(float2*)(g_lp + base + 0 * NB) = s0;
  *(float2*)(g_lp + base + 1 * NB) = s1;
  *(float2*)(g_lp + base + 2 * NB) = s2;
  *(float2*)(g_lp + base + 3 * NB) = s3;
}

// ---------------- LSTM finalize: reduce + bias + gating + state ------------
__global__ __launch_bounds__(256) void lstm_fin_kernel(
    int t, const float* __restrict__ bi, const float* __restrict__ bf,
    const float* __restrict__ bog, const float* __restrict__ bc) {
  const int flat = blockIdx.x * 256 + threadIdx.x;  // j*64 + b
  const int j = flat >> 6;
  float z[4];
#pragma unroll
  for (int g = 0; g < 4; ++g) {
    const float p0 = g_lp[(size_t)(0 * 4 + g) * NH * NB + flat];
    const float p1 = g_lp[(size_t)(1 * 4 + g) * NH * NB + flat];
    const float p2 = g_lp[(size_t)(2 * 4 + g) * NH * NB + flat];
    const float p3 = g_lp[(size_t)(3 * 4 + g) * NH * NB + flat];
    z[g] = ((p0 + p1) + p2) + p3;
  }
  const float zi = z[0] + bi[j];
  const float zf = z[1] + bf[j];
  const float zo = z[2] + bog[j];
  const float zc = z[3] + bc[j];
  const float iv = 1.0f / (1.0f + expf(-zi));
  const float fv = 1.0f / (1.0f + expf(-zf));
  const float ov = 1.0f / (1.0f + expf(-zo));
  const float cc = tanhf(zc);
  const float cold = g_cT[t & 1][flat];
  const float cn = fv * cold + iv * cc;
  g_cT[(t & 1) ^ 1][flat] = cn;
  g_A[(t & 1) ^ 1][NE * NB + flat] = ov * tanhf(cn);
}

// ---------------- logits partials: K split across blocks -------------------
// grid (313, 4): x = 32-vocab tile, y = 128-K chunk. Thread: 4 vocab
// (float4 Wo) x 2 batch (float2 LDS h). Wo element read exactly once.
__global__ __launch_bounds__(256) void logits_part_kernel(
    int t, const int* __restrict__ given_p, const float* __restrict__ Wo) {
  const int given = *given_p;
  if (t < given) return;
  __shared__ float hs[128 * NB];  // 32 KB K-chunk of h
  const int tid = threadIdx.x;
  const int kq = blockIdx.y;
  const int vq = tid & 7;
  const int bl0 = (tid >> 3) * 2;
  const int n = blockIdx.x * 32 + vq * 4;
  const bool nv = (n < NV);
  const int nl = nv ? n : 0;

  const float* hT = g_A[(t & 1) ^ 1] + NE * NB;
  {
    const float4* src = (const float4*)(hT + kq * 128 * NB);
    float4* dst = (float4*)hs;
#pragma unroll
    for (int i = 0; i < 8; ++i) dst[tid + i * 256] = src[tid + i * 256];
  }
  __syncthreads();

  float a00 = 0.f, a01 = 0.f, a02 = 0.f, a03 = 0.f;
  float a10 = 0.f, a11 = 0.f, a12 = 0.f, a13 = 0.f;
  const float* wpc = Wo + (size_t)kq * 128 * NV + nl;
#pragma unroll 8
  for (int kk = 0; kk < 128; ++kk) {
    const float4 w = *(const float4*)(wpc + (size_t)kk * NV);
    const float2 h2 = *(const float2*)(hs + kk * NB + bl0);
    a00 = fmaf(h2.x, w.x, a00); a01 = fmaf(h2.x, w.y, a01);
    a02 = fmaf(h2.x, w.z, a02); a03 = fmaf(h2.x, w.w, a03);
    a10 = fmaf(h2.y, w.x, a10); a11 = fmaf(h2.y, w.y, a11);
    a12 = fmaf(h2.y, w.z, a12); a13 = fmaf(h2.y, w.w, a13);
  }
  if (nv) {
    float4 r0; r0.x = a00; r0.y = a01; r0.z = a02; r0.w = a03;
    float4 r1; r1.x = a10; r1.y = a11; r1.z = a12; r1.w = a13;
    *(float4*)(g_part + (size_t)(kq * NB + bl0) * NV + n) = r0;
    *(float4*)(g_part + (size_t)(kq * NB + bl0 + 1) * NV + n) = r1;
  }
}

// ---------------- logits finalize: reduce + gumbel + argmax ----------------
// grid (313). Fixed reduce order ((p0+p1)+p2)+p3 + bo. Slot atomicMax only;
// token selection/gather moved to embed_kernel (kills the 1-block tail).
__global__ __launch_bounds__(256) void logits_fin_kernel(
    int t, const int* __restrict__ given_p, const float* __restrict__ bo) {
  const int given = *given_p;
  if (t < given) return;
  __shared__ unsigned long long best[NB];
  const int tid = threadIdx.x;
  const int vq = tid & 7;
  const int bl0 = (tid >> 3) * 2;
  const int n = blockIdx.x * 32 + vq * 4;
  const bool nv = (n < NV);
  const int nl = nv ? n : 0;
  if (tid < NB) best[tid] = 0ull;
  __syncthreads();

  if (nv) {
    const unsigned int key0 = g_keys[2 * t], key1 = g_keys[2 * t + 1];
    const float4 bo4 = *(const float4*)(bo + nl);
#pragma unroll
    for (int s = 0; s < 2; ++s) {
      const int bg = bl0 + s;
      const float4 p0 = *(const float4*)(g_part + (size_t)(0 * NB + bg) * NV + n);
      const float4 p1 = *(const float4*)(g_part + (size_t)(1 * NB + bg) * NV + n);
      const float4 p2 = *(const float4*)(g_part + (size_t)(2 * NB + bg) * NV + n);
      const float4 p3 = *(const float4*)(g_part + (size_t)(3 * NB + bg) * NV + n);
      float lg[4];
      lg[0] = ((p0.x + p1.x) + p2.x) + p3.x + bo4.x;
      lg[1] = ((p0.y + p1.y) + p2.y) + p3.y + bo4.y;
      lg[2] = ((p0.z + p1.z) + p2.z) + p3.z + bo4.z;
      lg[3] = ((p0.w + p1.w) + p2.w) + p3.w + bo4.w;
      unsigned long long bp = 0ull;
#pragma unroll
      for (int jj = 0; jj < 4; ++jj) {
        const int v = n + jj;
        unsigned int u0, u1, bits;
#if PARTITIONABLE
        threefry2x32(key0, key1, 0u, (unsigned int)(bg * NV + v), u0, u1);
        bits = u0 ^ u1;
#else
        const int p = bg * NV + v;
        const unsigned int c = (unsigned int)(p >= (NB / 2) * NV ? p - (NB / 2) * NV : p);
        threefry2x32(key0, key1, c, c + (unsigned int)((NB / 2) * NV), u0, u1);
        bits = (p >= (NB / 2) * NV) ? u1 : u0;
#endif
        const float val = gumbel_from_bits(bits) + lg[jj];
        const unsigned int fb = __float_as_uint(val);
        const unsigned int ord = (fb & 0x80000000u) ? ~fb : (fb | 0x80000000u);
        const unsigned long long pk =
            ((unsigned long long)ord << 32) | (unsigned int)(~v);
        bp = (pk > bp) ? pk : bp;
      }
      atomicMax(&best[bg], bp);
    }
  }
  __syncthreads();
  if (tid < NB) atomicMax(&g_slots[t * NB + tid], best[tid]);
}

// ---------------- token select + out write + embedding gather --------------
// grid (16): block covers contiguous 16 k-rows x all 64 b. Lane = b ->
// coalesced x^T writes; per-(b,block) emb reads hit one 64B line.
// Kernel boundary after logits_fin replaces the old ticket/fence.
__global__ __launch_bounds__(256) void embed_kernel(
    int t, const int* __restrict__ input_x, const int* __restrict__ given_p,
    const float* __restrict__ emb) {
  __shared__ int toksh[NB];
  const int tid = threadIdx.x;
  const int given = *given_p;
  if (tid < NB) {
    int tok;
    if (t < given) {
      tok = input_x[tid * NT + t];
    } else {
      const unsigned long long pk = g_slots[t * NB + tid];
      tok = (int)(~(unsigned int)(pk & 0xFFFFFFFFull));
    }
    toksh[tid] = tok;
  }
  __syncthreads();
  float* xdst = g_A[(t + 1) & 1];  // x-part of the buffer step t+1 reads
#pragma unroll
  for (int p = 0; p < 4; ++p) {
    const int i = blockIdx.x * 1024 + p * 256 + tid;  // k*64 + b
    const int b = i & 63, k = i >> 6;
    xdst[i] = emb[toksh[b] * NE + k];
  }
}

// out-write kernel piece folded into embed would add a divergent branch for
// all blocks; separate tiny kernel is cheaper to reason about:
__global__ void token_out_kernel(int t, const int* __restrict__ input_x,
                                 const int* __restrict__ given_p,
                                 int* __restrict__ out) {
  const int b = threadIdx.x;
  if (b >= NB) return;
  const int given = *given_p;
  int tok;
  if (t < given) {
    tok = input_x[b * NT + t];
  } else {
    const unsigned long long pk = g_slots[t * NB + b];
    tok = (int)(~(unsigned int)(pk & 0xFFFFFFFFull));
  }
  out[b * NT + t] = tok;
}

// ---------------- host launch ----------------------------------------------
extern "C" void kernel_launch(void* const* d_in, const int* in_sizes, int n_in,
                              void* d_out, int out_size, void* d_ws, size_t ws_size,
                              hipStream_t stream) {
  const int* input_x = (const int*)d_in[0];
  const int* given_num = (const int*)d_in[1];
  const int* start_tok = (const int*)d_in[2];
  const float* emb = (const float*)d_in[3];
  const float* Wi = (const float*)d_in[4];
  const float* Ui = (const float*)d_in[5];
  const float* bi = (const float*)d_in[6];
  const float* Wf = (const float*)d_in[7];
  const float* Uf = (const float*)d_in[8];
  const float* bf = (const float*)d_in[9];
  const float* Wog = (const float*)d_in[10];
  const float* Uog = (const float*)d_in[11];
  const float* bog = (const float*)d_in[12];
  const float* Wc = (const float*)d_in[13];
  const float* Uc = (const float*)d_in[14];
  const float* bc = (const float*)d_in[15];
  const float* Wo = (const float*)d_in[16];
  const float* bo = (const float*)d_in[17];
  int* out = (int*)d_out;

  init_kernel<<<128, 256, 0, stream>>>(start_tok, emb);
  for (int t = 0; t < NT; ++t) {
    lstm_part_kernel<<<dim3(16, 4, 4), 256, 0, stream>>>(t, Wi, Ui, Wf, Uf,
                                                         Wog, Uog, Wc, Uc);
    lstm_fin_kernel<<<128, 256, 0, stream>>>(t, bi, bf, bog, bc);
    logits_part_kernel<<<dim3(313, 4), 256, 0, stream>>>(t, given_num, Wo);
    logits_fin_kernel<<<313, 256, 0, stream>>>(t, given_num, bo);
    embed_kernel<<<16, 256, 0, stream>>>(t, input_x, given_num, emb);
    token_out_kernel<<<1, 64, 0, stream>>>(t, input_x, given_num, out);
  }
}